// Round 12
// baseline (115.936 us; speedup 1.0000x reference)
//
#include <hip/hip_runtime.h>
#include <math.h>

#define IN_NODES 1152
#define OUT_NODES 10
#define IN_DIM 8
#define OUT_DIM 16
#define BATCH 256
#define KTILES 288       // K = 9216 = 288 tiles of 32
#define KT_PER_W 36      // 288 / 8 waves
#define NBT 16           // b-tiles of 16

typedef __attribute__((ext_vector_type(8))) short bf16x8;
typedef __attribute__((ext_vector_type(4))) float f32x4;

__device__ __forceinline__ unsigned short f2bf(float f) {
    unsigned u = __float_as_uint(f);
    u += 0x7FFF + ((u >> 16) & 1);   // round-to-nearest-even
    return (unsigned short)(u >> 16);
}
__device__ __forceinline__ float bf2f(unsigned short h) {
    return __uint_as_float(((unsigned)h) << 16);
}
__device__ __forceinline__ void split8(const float* vals, bf16x8& vh, bf16x8& vl) {
#pragma unroll
    for (int e = 0; e < 8; ++e) {
        unsigned short h = f2bf(vals[e]);
        vh[e] = (short)h;
        vl[e] = (short)f2bf(vals[e] - bf2f(h));
    }
}

// async global->LDS, 16B per lane
__device__ __forceinline__ void ld16(const void* g, void* l) {
    __builtin_amdgcn_global_load_lds(
        (const __attribute__((address_space(1))) unsigned int*)g,
        (__attribute__((address_space(3))) unsigned int*)l, 16, 0, 0);
}

// ---------------------------------------------------------------------------
// Pack layouts (validated rounds 5/8/9/10):
//  B slot sl = (bt*KTILES + kt)*64 + lane, lane = (i&3)*16 + (b&15), elem = k.
//  A slot s  = (j*KTILES + kt)*64 + lane, lane = (i&3)*16 + d, elem = k.
//  C tile:   col = lane&15 (b), row = (lane>>4)*4 + r (d).
// ---------------------------------------------------------------------------

// k_prep: blocks 0..1151: xr + B-pack.  blocks 1152..1871: A-pack (c = 0.1).
__global__ __launch_bounds__(256) void k_prep(const float* __restrict__ x,
                                              const float* __restrict__ W,
                                              float* __restrict__ xr,
                                              unsigned short* __restrict__ Bhi,
                                              unsigned short* __restrict__ Blo,
                                              unsigned short* __restrict__ Ahi,
                                              unsigned short* __restrict__ Alo) {
    const int bid = blockIdx.x;
    const int tid = threadIdx.x;
    if (bid < IN_NODES) {
        const int i = bid, b = tid;
        const float4* xp = (const float4*)(x + ((size_t)b * IN_NODES + i) * IN_DIM);
        float4 a0 = xp[0], a1 = xp[1];
        float4* xd = (float4*)(xr + ((size_t)i * BATCH + b) * IN_DIM);
        xd[0] = a0; xd[1] = a1;
        float vals[8] = {a0.x, a0.y, a0.z, a0.w, a1.x, a1.y, a1.z, a1.w};
        bf16x8 vh, vl; split8(vals, vh, vl);
        size_t sl = ((size_t)(b >> 4) * KTILES + (i >> 2)) * 64 + (i & 3) * 16 + (b & 15);
        *(bf16x8*)(Bhi + sl * 8) = vh;
        *(bf16x8*)(Blo + sl * 8) = vl;
    } else {
        const int s = (bid - IN_NODES) * 256 + tid;   // 0..184319
        const int j = s / (KTILES * 64);
        const int rem = s % (KTILES * 64);
        const int kt = rem >> 6;
        const int l = rem & 63;
        const int i = kt * 4 + (l >> 4);
        const int d = l & 15;
        const float4* wp = (const float4*)(W +
            (((size_t)i * OUT_NODES + j) * OUT_DIM + d) * IN_DIM);
        float4 w0 = wp[0], w1 = wp[1];
        const float c = 1.0f / OUT_NODES;
        float vals[8] = {c * w0.x, c * w0.y, c * w0.z, c * w0.w,
                         c * w1.x, c * w1.y, c * w1.z, c * w1.w};
        bf16x8 vh, vl; split8(vals, vh, vl);
        *(bf16x8*)(Ahi + (size_t)s * 8) = vh;
        *(bf16x8*)(Alo + (size_t)s * 8) = vl;
    }
}

// ---------------------------------------------------------------------------
// k_gr: fused GEMM + reduce + squash, XCD-locality-aware grid mapping.
// grid 160, 512 thr = 8 waves; wave w = K-chunk w (36 k-tiles).
//   xcd = bid&7, q = bid>>3:  j = q>>1, bt = xcd*2 + (q&1)
// => each XCD owns a bt-pair: per-phase L2 set = A(all j) slice + B(2 bt)
//    slice ~= 1.8 MB < 4 MB XCD-L2 (round-11's mapping thrashed 7.1 MB).
// MFMA split-bf16 -> LDS cross-wave reduce (fixed order) -> squash -> v/out.
// ---------------------------------------------------------------------------
__global__ __launch_bounds__(512) void k_gr(const unsigned short* __restrict__ Ahi,
                                            const unsigned short* __restrict__ Alo,
                                            const unsigned short* __restrict__ Bhi,
                                            const unsigned short* __restrict__ Blo,
                                            float* __restrict__ v,
                                            float* __restrict__ out,
                                            int write_out) {
    __shared__ __align__(16) float red[8][64][4];   // 8 KB

    const int bid = blockIdx.x;
    const int xcd = bid & 7;
    const int q = bid >> 3;            // 0..19
    const int j = q >> 1;              // 0..9
    const int bt = xcd * 2 + (q & 1);  // 0..15
    const int w = threadIdx.x >> 6;
    const int lane = threadIdx.x & 63;

    const size_t ab = (((size_t)j * KTILES + w * KT_PER_W) * 64 + lane) * 8;
    const size_t bb = (((size_t)bt * KTILES + w * KT_PER_W) * 64 + lane) * 8;

    f32x4 acc0 = {0.f, 0.f, 0.f, 0.f}, acc1 = acc0, acc2 = acc0;
#pragma unroll 3
    for (int kt = 0; kt < KT_PER_W; ++kt) {
        bf16x8 ah = *(const bf16x8*)(Ahi + ab + (size_t)kt * 512);
        bf16x8 al = *(const bf16x8*)(Alo + ab + (size_t)kt * 512);
        bf16x8 bh = *(const bf16x8*)(Bhi + bb + (size_t)kt * 512);
        bf16x8 bl = *(const bf16x8*)(Blo + bb + (size_t)kt * 512);
        acc0 = __builtin_amdgcn_mfma_f32_16x16x32_bf16(ah, bh, acc0, 0, 0, 0);
        acc1 = __builtin_amdgcn_mfma_f32_16x16x32_bf16(ah, bl, acc1, 0, 0, 0);
        acc2 = __builtin_amdgcn_mfma_f32_16x16x32_bf16(al, bh, acc2, 0, 0, 0);
    }
    f32x4 acc = acc0 + acc1 + acc2;
    *(f32x4*)&red[w][lane][0] = acc;
    __syncthreads();

    if (w == 0) {
        f32x4 s = {0.f, 0.f, 0.f, 0.f};
#pragma unroll
        for (int p = 0; p < 8; ++p) s += *(const f32x4*)&red[p][lane][0];
        float sq = s[0] * s[0] + s[1] * s[1] + s[2] * s[2] + s[3] * s[3];
        sq += __shfl_xor(sq, 16);
        sq += __shfl_xor(sq, 32);
        float scale = sq / ((1.0f + sq) * sqrtf(sq));
        f32x4 vv = s * scale;
        const int b = bt * 16 + (lane & 15);
        const int d0 = (lane >> 4) * 4;
        *(f32x4*)(v + ((size_t)j * BATCH + b) * OUT_DIM + d0) = vv;
        if (write_out)
            *(f32x4*)(out + ((size_t)b * OUT_NODES + j) * OUT_DIM + d0) = vv;
    }
}

// ---------------------------------------------------------------------------
// k_agree: b-parallel (validated round 10). grid 1152 (block=i), 256 thr (b).
// W[i] in LDS; coalesced dots; wave+LDS reduce; softmax; c*W -> A-pack fold.
// ---------------------------------------------------------------------------
__global__ __launch_bounds__(256) void k_agree(const float* __restrict__ W,
                                               const float* __restrict__ xr,
                                               const float* __restrict__ v,
                                               float* __restrict__ blog,
                                               unsigned short* __restrict__ Ahi,
                                               unsigned short* __restrict__ Alo,
                                               int it) {
    __shared__ __align__(16) float W_s[1280];
    __shared__ float red[4][OUT_NODES];
    __shared__ float csh[OUT_NODES];

    const int i = blockIdx.x;
    const int tid = threadIdx.x;
    const int w = tid >> 6, lane = tid & 63;

    {
        const char* gw = (const char*)W + (size_t)i * 5120;
        ld16(gw + tid * 16, (char*)W_s + tid * 16);
        if (tid < 64) ld16(gw + 4096 + tid * 16, (char*)W_s + 4096 + tid * 16);
    }
    asm volatile("s_waitcnt vmcnt(0)" ::: "memory");
    __syncthreads();

    const int b = tid;
    const float4* xp = (const float4*)(xr + ((size_t)i * BATCH + b) * IN_DIM);
    const float4 x0 = xp[0], x1 = xp[1];

#pragma unroll 2
    for (int j = 0; j < OUT_NODES; ++j) {
        const float4* vp = (const float4*)(v + ((size_t)j * BATCH + b) * OUT_DIM);
        float4 v0 = vp[0], v1 = vp[1], v2 = vp[2], v3 = vp[3];
        float vv[16] = {v0.x, v0.y, v0.z, v0.w, v1.x, v1.y, v1.z, v1.w,
                        v2.x, v2.y, v2.z, v2.w, v3.x, v3.y, v3.z, v3.w};
        float s0 = 0.f, s1 = 0.f, s2 = 0.f, s3 = 0.f;
#pragma unroll
        for (int d = 0; d < OUT_DIM; ++d) {
            float4 w0 = *(const float4*)&W_s[(j * 16 + d) * 8];
            float4 w1 = *(const float4*)&W_s[(j * 16 + d) * 8 + 4];
            float u = w0.x * x0.x;
            u = fmaf(w0.y, x0.y, u); u = fmaf(w0.z, x0.z, u);
            u = fmaf(w0.w, x0.w, u); u = fmaf(w1.x, x1.x, u);
            u = fmaf(w1.y, x1.y, u); u = fmaf(w1.z, x1.z, u);
            u = fmaf(w1.w, x1.w, u);
            if ((d & 3) == 0) s0 = fmaf(u, vv[d], s0);
            else if ((d & 3) == 1) s1 = fmaf(u, vv[d], s1);
            else if ((d & 3) == 2) s2 = fmaf(u, vv[d], s2);
            else s3 = fmaf(u, vv[d], s3);
        }
        float sum = (s0 + s1) + (s2 + s3);
        sum += __shfl_xor(sum, 1);
        sum += __shfl_xor(sum, 2);
        sum += __shfl_xor(sum, 4);
        sum += __shfl_xor(sum, 8);
        sum += __shfl_xor(sum, 16);
        sum += __shfl_xor(sum, 32);
        if (lane == 0) red[w][j] = sum;
    }
    __syncthreads();

    if (tid < OUT_NODES) {
        float a = (red[0][tid] + red[1][tid]) + (red[2][tid] + red[3][tid]);
        float bn = (it == 0 ? 0.f : blog[i * OUT_NODES + tid]) + a * (1.0f / BATCH);
        if (it == 0) blog[i * OUT_NODES + tid] = bn;
        red[0][tid] = bn;                 // reuse red row 0 for logits
    }
    __syncthreads();

    if (tid < OUT_NODES) {
        float m = red[0][0];
#pragma unroll
        for (int jj = 1; jj < OUT_NODES; ++jj) m = fmaxf(m, red[0][jj]);
        float ssum = 0.f;
#pragma unroll
        for (int jj = 0; jj < OUT_NODES; ++jj) ssum += __expf(red[0][jj] - m);
        csh[tid] = __expf(red[0][tid] - m) / ssum;
    }
    __syncthreads();

    if (tid < OUT_NODES * OUT_DIM) {
        const int j = tid >> 4;
        const int d = tid & 15;
        const float c = csh[j];
        const float* wrow = &W_s[(j * 16 + d) * 8];
        float vals[8] = {c * wrow[0], c * wrow[1], c * wrow[2], c * wrow[3],
                         c * wrow[4], c * wrow[5], c * wrow[6], c * wrow[7]};
        bf16x8 vh, vl; split8(vals, vh, vl);
        size_t sl = ((size_t)j * KTILES + (i >> 2)) * 64 + (i & 3) * 16 + d;
        *(bf16x8*)(Ahi + sl * 8) = vh;
        *(bf16x8*)(Alo + sl * 8) = vl;
    }
}

// ---------------------------------------------------------------------------
extern "C" void kernel_launch(void* const* d_in, const int* in_sizes, int n_in,
                              void* d_out, int out_size, void* d_ws, size_t ws_size,
                              hipStream_t stream) {
    const float* x = (const float*)d_in[0];  // [256,1152,8]
    const float* W = (const float*)d_in[1];  // [1152,10,16,8]
    float* out = (float*)d_out;              // [256,10,16,1]

    char* p = (char*)d_ws;
    float* xr = (float*)p;                     p += (size_t)IN_NODES * BATCH * IN_DIM * 4;
    unsigned short* Bhi = (unsigned short*)p;  p += (size_t)NBT * KTILES * 64 * 8 * 2;
    unsigned short* Blo = (unsigned short*)p;  p += (size_t)NBT * KTILES * 64 * 8 * 2;
    unsigned short* Ahi = (unsigned short*)p;  p += (size_t)OUT_NODES * KTILES * 64 * 8 * 2;
    unsigned short* Alo = (unsigned short*)p;  p += (size_t)OUT_NODES * KTILES * 64 * 8 * 2;
    float* v = (float*)p;                      p += (size_t)OUT_NODES * BATCH * OUT_DIM * 4;
    float* blog = (float*)p;                   p += (size_t)IN_NODES * OUT_NODES * 4;
    // total ~34 MB of ws

    k_prep<<<IN_NODES + 720, 256, 0, stream>>>(x, W, xr, Bhi, Blo, Ahi, Alo);

    for (int it = 0; it < 3; ++it) {
        k_gr<<<160, 512, 0, stream>>>(Ahi, Alo, Bhi, Blo, v, out, it == 2 ? 1 : 0);
        if (it < 2)
            k_agree<<<IN_NODES, 256, 0, stream>>>(W, xr, v, blog, Ahi, Alo, it);
    }
}

// Round 13
// 93.538 us; speedup vs baseline: 1.2394x; 1.2394x over previous
//
#include <hip/hip_runtime.h>
#include <math.h>

#define IN_NODES 1152
#define OUT_NODES 10
#define IN_DIM 8
#define OUT_DIM 16
#define BATCH 256
#define KTILES 288       // K = 9216 = 288 tiles of 32
#define KC 16            // split-K chunks
#define KT_PER_KC 18     // 288 / 16
#define NBT 16           // b-tiles of 16

typedef __attribute__((ext_vector_type(8))) short bf16x8;
typedef __attribute__((ext_vector_type(4))) float f32x4;

__device__ __forceinline__ unsigned short f2bf(float f) {
    unsigned u = __float_as_uint(f);
    u += 0x7FFF + ((u >> 16) & 1);   // round-to-nearest-even
    return (unsigned short)(u >> 16);
}
__device__ __forceinline__ float bf2f(unsigned short h) {
    return __uint_as_float(((unsigned)h) << 16);
}
__device__ __forceinline__ void split8(const float* vals, bf16x8& vh, bf16x8& vl) {
#pragma unroll
    for (int e = 0; e < 8; ++e) {
        unsigned short h = f2bf(vals[e]);
        vh[e] = (short)h;
        vl[e] = (short)f2bf(vals[e] - bf2f(h));
    }
}

// async global->LDS, 16B per lane
__device__ __forceinline__ void ld16(const void* g, void* l) {
    __builtin_amdgcn_global_load_lds(
        (const __attribute__((address_space(1))) unsigned int*)g,
        (__attribute__((address_space(3))) unsigned int*)l, 16, 0, 0);
}

// ---------------------------------------------------------------------------
// Pack layouts (validated rounds 5/8/9/10):
//  B slot sl = (bt*KTILES + kt)*64 + lane, lane = (i&3)*16 + (b&15), elem = k.
//  A slot s  = (j*KTILES + kt)*64 + lane, lane = (i&3)*16 + d, elem = k.
//  C tile:   col = lane&15 (b), row = (lane>>4)*4 + r (d).
// Precision: A = bf16 hi+lo (exact), B = bf16 hi only.
//  (ah+al)*bh exact in A; residual a*(b-bh) ~1.5e-4 on v, 100x under floor.
// ---------------------------------------------------------------------------

// k_prep: blocks 0..1151: xr + B-pack (hi).  blocks 1152..1871: A-pack (c=0.1).
__global__ __launch_bounds__(256) void k_prep(const float* __restrict__ x,
                                              const float* __restrict__ W,
                                              float* __restrict__ xr,
                                              unsigned short* __restrict__ Bhi,
                                              unsigned short* __restrict__ Ahi,
                                              unsigned short* __restrict__ Alo) {
    const int bid = blockIdx.x;
    const int tid = threadIdx.x;
    if (bid < IN_NODES) {
        const int i = bid, b = tid;
        const float4* xp = (const float4*)(x + ((size_t)b * IN_NODES + i) * IN_DIM);
        float4 a0 = xp[0], a1 = xp[1];
        float4* xd = (float4*)(xr + ((size_t)i * BATCH + b) * IN_DIM);
        xd[0] = a0; xd[1] = a1;
        float vals[8] = {a0.x, a0.y, a0.z, a0.w, a1.x, a1.y, a1.z, a1.w};
        bf16x8 vh;
#pragma unroll
        for (int e = 0; e < 8; ++e) vh[e] = (short)f2bf(vals[e]);
        size_t sl = ((size_t)(b >> 4) * KTILES + (i >> 2)) * 64 + (i & 3) * 16 + (b & 15);
        *(bf16x8*)(Bhi + sl * 8) = vh;
    } else {
        const int s = (bid - IN_NODES) * 256 + tid;   // 0..184319
        const int j = s / (KTILES * 64);
        const int rem = s % (KTILES * 64);
        const int kt = rem >> 6;
        const int l = rem & 63;
        const int i = kt * 4 + (l >> 4);
        const int d = l & 15;
        const float4* wp = (const float4*)(W +
            (((size_t)i * OUT_NODES + j) * OUT_DIM + d) * IN_DIM);
        float4 w0 = wp[0], w1 = wp[1];
        const float c = 1.0f / OUT_NODES;
        float vals[8] = {c * w0.x, c * w0.y, c * w0.z, c * w0.w,
                         c * w1.x, c * w1.y, c * w1.z, c * w1.w};
        bf16x8 vh, vl; split8(vals, vh, vl);
        *(bf16x8*)(Ahi + (size_t)s * 8) = vh;
        *(bf16x8*)(Alo + (size_t)s * 8) = vl;
    }
}

// ---------------------------------------------------------------------------
// k_gemm: grid 640 = (j=10, btg=4, kc=16), 256 thr (4 waves, wave -> bt).
// 2 MFMA/ktile: (ah + al) x bh. Fence-free split-K partials.
// ---------------------------------------------------------------------------
__global__ __launch_bounds__(256) void k_gemm(const unsigned short* __restrict__ Ahi,
                                              const unsigned short* __restrict__ Alo,
                                              const unsigned short* __restrict__ Bhi,
                                              float* __restrict__ part) {
    const int bid = blockIdx.x;
    const int j = bid >> 6;            // /64
    const int r = bid & 63;
    const int btg = r >> 4;
    const int kc = r & 15;
    const int tid = threadIdx.x;
    const int lane = tid & 63;
    const int bt = btg * 4 + (tid >> 6);

    const size_t ab = (((size_t)j * KTILES + kc * KT_PER_KC) * 64 + lane) * 8;
    const size_t bb = (((size_t)bt * KTILES + kc * KT_PER_KC) * 64 + lane) * 8;

    f32x4 acc0 = {0.f, 0.f, 0.f, 0.f}, acc1 = acc0;
#pragma unroll 3
    for (int kt = 0; kt < KT_PER_KC; ++kt) {
        bf16x8 ah = *(const bf16x8*)(Ahi + ab + (size_t)kt * 512);
        bf16x8 al = *(const bf16x8*)(Alo + ab + (size_t)kt * 512);
        bf16x8 bh = *(const bf16x8*)(Bhi + bb + (size_t)kt * 512);
        acc0 = __builtin_amdgcn_mfma_f32_16x16x32_bf16(ah, bh, acc0, 0, 0, 0);
        acc1 = __builtin_amdgcn_mfma_f32_16x16x32_bf16(al, bh, acc1, 0, 0, 0);
    }
    f32x4 acc = acc0 + acc1;
    *(f32x4*)(part + (((size_t)kc * OUT_NODES + j) * NBT + bt) * 1024 + lane * 4) = acc;
}

// ---------------------------------------------------------------------------
// k_reduce: grid 160 = (j,bt), 64 thr. Sum over kc (fixed order) + squash.
// ---------------------------------------------------------------------------
__global__ __launch_bounds__(64) void k_reduce(const float* __restrict__ part,
                                               float* __restrict__ v,
                                               float* __restrict__ out,
                                               int write_out) {
    const int j = blockIdx.x >> 4;
    const int bt = blockIdx.x & 15;
    const int lane = threadIdx.x;

    f32x4 s = {0.f, 0.f, 0.f, 0.f};
#pragma unroll
    for (int kc = 0; kc < KC; ++kc)
        s += *(const f32x4*)(part + (((size_t)kc * OUT_NODES + j) * NBT + bt) * 1024 +
                             lane * 4);
    float sq = s[0] * s[0] + s[1] * s[1] + s[2] * s[2] + s[3] * s[3];
    sq += __shfl_xor(sq, 16);
    sq += __shfl_xor(sq, 32);
    float scale = sq / ((1.0f + sq) * sqrtf(sq));
    f32x4 vv = s * scale;
    const int b = bt * 16 + (lane & 15);
    const int d0 = (lane >> 4) * 4;
    *(f32x4*)(v + ((size_t)j * BATCH + b) * OUT_DIM + d0) = vv;
    if (write_out)
        *(f32x4*)(out + ((size_t)b * OUT_NODES + j) * OUT_DIM + d0) = vv;
}

// ---------------------------------------------------------------------------
// k_agree: b-parallel (validated round 10). grid 1152 (block=i), 256 thr (b).
// W[i] in LDS; coalesced dots; wave+LDS reduce; softmax; c*W -> A-pack fold.
// ---------------------------------------------------------------------------
__global__ __launch_bounds__(256) void k_agree(const float* __restrict__ W,
                                               const float* __restrict__ xr,
                                               const float* __restrict__ v,
                                               float* __restrict__ blog,
                                               unsigned short* __restrict__ Ahi,
                                               unsigned short* __restrict__ Alo,
                                               int it) {
    __shared__ __align__(16) float W_s[1280];
    __shared__ float red[4][OUT_NODES];
    __shared__ float csh[OUT_NODES];

    const int i = blockIdx.x;
    const int tid = threadIdx.x;
    const int w = tid >> 6, lane = tid & 63;

    {
        const char* gw = (const char*)W + (size_t)i * 5120;
        ld16(gw + tid * 16, (char*)W_s + tid * 16);
        if (tid < 64) ld16(gw + 4096 + tid * 16, (char*)W_s + 4096 + tid * 16);
    }
    asm volatile("s_waitcnt vmcnt(0)" ::: "memory");
    __syncthreads();

    const int b = tid;
    const float4* xp = (const float4*)(xr + ((size_t)i * BATCH + b) * IN_DIM);
    const float4 x0 = xp[0], x1 = xp[1];

#pragma unroll 2
    for (int j = 0; j < OUT_NODES; ++j) {
        const float4* vp = (const float4*)(v + ((size_t)j * BATCH + b) * OUT_DIM);
        float4 v0 = vp[0], v1 = vp[1], v2 = vp[2], v3 = vp[3];
        float vv[16] = {v0.x, v0.y, v0.z, v0.w, v1.x, v1.y, v1.z, v1.w,
                        v2.x, v2.y, v2.z, v2.w, v3.x, v3.y, v3.z, v3.w};
        float s0 = 0.f, s1 = 0.f, s2 = 0.f, s3 = 0.f;
#pragma unroll
        for (int d = 0; d < OUT_DIM; ++d) {
            float4 w0 = *(const float4*)&W_s[(j * 16 + d) * 8];
            float4 w1 = *(const float4*)&W_s[(j * 16 + d) * 8 + 4];
            float u = w0.x * x0.x;
            u = fmaf(w0.y, x0.y, u); u = fmaf(w0.z, x0.z, u);
            u = fmaf(w0.w, x0.w, u); u = fmaf(w1.x, x1.x, u);
            u = fmaf(w1.y, x1.y, u); u = fmaf(w1.z, x1.z, u);
            u = fmaf(w1.w, x1.w, u);
            if ((d & 3) == 0) s0 = fmaf(u, vv[d], s0);
            else if ((d & 3) == 1) s1 = fmaf(u, vv[d], s1);
            else if ((d & 3) == 2) s2 = fmaf(u, vv[d], s2);
            else s3 = fmaf(u, vv[d], s3);
        }
        float sum = (s0 + s1) + (s2 + s3);
        sum += __shfl_xor(sum, 1);
        sum += __shfl_xor(sum, 2);
        sum += __shfl_xor(sum, 4);
        sum += __shfl_xor(sum, 8);
        sum += __shfl_xor(sum, 16);
        sum += __shfl_xor(sum, 32);
        if (lane == 0) red[w][j] = sum;
    }
    __syncthreads();

    if (tid < OUT_NODES) {
        float a = (red[0][tid] + red[1][tid]) + (red[2][tid] + red[3][tid]);
        float bn = (it == 0 ? 0.f : blog[i * OUT_NODES + tid]) + a * (1.0f / BATCH);
        if (it == 0) blog[i * OUT_NODES + tid] = bn;
        red[0][tid] = bn;                 // reuse red row 0 for logits
    }
    __syncthreads();

    if (tid < OUT_NODES) {
        float m = red[0][0];
#pragma unroll
        for (int jj = 1; jj < OUT_NODES; ++jj) m = fmaxf(m, red[0][jj]);
        float ssum = 0.f;
#pragma unroll
        for (int jj = 0; jj < OUT_NODES; ++jj) ssum += __expf(red[0][jj] - m);
        csh[tid] = __expf(red[0][tid] - m) / ssum;
    }
    __syncthreads();

    if (tid < OUT_NODES * OUT_DIM) {
        const int j = tid >> 4;
        const int d = tid & 15;
        const float c = csh[j];
        const float* wrow = &W_s[(j * 16 + d) * 8];
        float vals[8] = {c * wrow[0], c * wrow[1], c * wrow[2], c * wrow[3],
                         c * wrow[4], c * wrow[5], c * wrow[6], c * wrow[7]};
        bf16x8 vh, vl; split8(vals, vh, vl);
        size_t sl = ((size_t)j * KTILES + (i >> 2)) * 64 + (i & 3) * 16 + d;
        *(bf16x8*)(Ahi + sl * 8) = vh;
        *(bf16x8*)(Alo + sl * 8) = vl;
    }
}

// ---------------------------------------------------------------------------
extern "C" void kernel_launch(void* const* d_in, const int* in_sizes, int n_in,
                              void* d_out, int out_size, void* d_ws, size_t ws_size,
                              hipStream_t stream) {
    const float* x = (const float*)d_in[0];  // [256,1152,8]
    const float* W = (const float*)d_in[1];  // [1152,10,16,8]
    float* out = (float*)d_out;              // [256,10,16,1]

    char* p = (char*)d_ws;
    float* xr = (float*)p;                     p += (size_t)IN_NODES * BATCH * IN_DIM * 4;
    unsigned short* Bhi = (unsigned short*)p;  p += (size_t)NBT * KTILES * 64 * 8 * 2;
    unsigned short* Ahi = (unsigned short*)p;  p += (size_t)OUT_NODES * KTILES * 64 * 8 * 2;
    unsigned short* Alo = (unsigned short*)p;  p += (size_t)OUT_NODES * KTILES * 64 * 8 * 2;
    float* part = (float*)p;                   p += (size_t)KC * OUT_NODES * NBT * 1024 * 4;
    float* v = (float*)p;                      p += (size_t)OUT_NODES * BATCH * OUT_DIM * 4;
    float* blog = (float*)p;                   p += (size_t)IN_NODES * OUT_NODES * 4;
    // total ~31 MB of ws

    k_prep<<<IN_NODES + 720, 256, 0, stream>>>(x, W, xr, Bhi, Ahi, Alo);

    for (int it = 0; it < 3; ++it) {
        k_gemm<<<640, 256, 0, stream>>>(Ahi, Alo, Bhi, part);
        k_reduce<<<160, 64, 0, stream>>>(part, v, out, it == 2 ? 1 : 0);
        if (it < 2)
            k_agree<<<IN_NODES, 256, 0, stream>>>(W, xr, v, blog, Ahi, Alo, it);
    }
}

// Round 14
// 81.616 us; speedup vs baseline: 1.4205x; 1.1461x over previous
//
#include <hip/hip_runtime.h>
#include <math.h>

#define IN_NODES 1152
#define OUT_NODES 10
#define IN_DIM 8
#define OUT_DIM 16
#define BATCH 256
#define KTILES 288       // K = 9216 = 288 tiles of 32
#define KC 16            // split-K chunks
#define KT_PER_KC 18     // 288 / 16
#define NBT 16           // b-tiles of 16

typedef __attribute__((ext_vector_type(8))) short bf16x8;
typedef __attribute__((ext_vector_type(4))) float f32x4;

__device__ __forceinline__ unsigned short f2bf(float f) {
    unsigned u = __float_as_uint(f);
    u += 0x7FFF + ((u >> 16) & 1);   // round-to-nearest-even
    return (unsigned short)(u >> 16);
}

// async global->LDS, 16B per lane
__device__ __forceinline__ void ld16(const void* g, void* l) {
    __builtin_amdgcn_global_load_lds(
        (const __attribute__((address_space(1))) unsigned int*)g,
        (__attribute__((address_space(3))) unsigned int*)l, 16, 0, 0);
}

// ---------------------------------------------------------------------------
// Pack layouts (validated rounds 5/8/9/10/13):
//  B slot sl = (bt*KTILES + kt)*64 + lane, lane = (i&3)*16 + (b&15), elem = k.
//  A slot s  = (j*KTILES + kt)*64 + lane, lane = (i&3)*16 + d, elem = k.
//  C tile:   col = lane&15 (b), row = (lane>>4)*4 + r (d).
// Precision: A and B both single bf16 (RNE). Per-product rel err ~2^-8;
//  over K=9216 random-sign terms -> delta-v ~1e-3; measured path B-only gave
//  absmax 0.0039, A adds ~same independently -> ~0.006 < 0.0159 threshold.
// ---------------------------------------------------------------------------

// k_prep: blocks 0..1151: xr + B-pack.  blocks 1152..1871: A-pack (c = 0.1).
__global__ __launch_bounds__(256) void k_prep(const float* __restrict__ x,
                                              const float* __restrict__ W,
                                              float* __restrict__ xr,
                                              unsigned short* __restrict__ Bhi,
                                              unsigned short* __restrict__ Ahi) {
    const int bid = blockIdx.x;
    const int tid = threadIdx.x;
    if (bid < IN_NODES) {
        const int i = bid, b = tid;
        const float4* xp = (const float4*)(x + ((size_t)b * IN_NODES + i) * IN_DIM);
        float4 a0 = xp[0], a1 = xp[1];
        float4* xd = (float4*)(xr + ((size_t)i * BATCH + b) * IN_DIM);
        xd[0] = a0; xd[1] = a1;
        float vals[8] = {a0.x, a0.y, a0.z, a0.w, a1.x, a1.y, a1.z, a1.w};
        bf16x8 vh;
#pragma unroll
        for (int e = 0; e < 8; ++e) vh[e] = (short)f2bf(vals[e]);
        size_t sl = ((size_t)(b >> 4) * KTILES + (i >> 2)) * 64 + (i & 3) * 16 + (b & 15);
        *(bf16x8*)(Bhi + sl * 8) = vh;
    } else {
        const int s = (bid - IN_NODES) * 256 + tid;   // 0..184319
        const int j = s / (KTILES * 64);
        const int rem = s % (KTILES * 64);
        const int kt = rem >> 6;
        const int l = rem & 63;
        const int i = kt * 4 + (l >> 4);
        const int d = l & 15;
        const float4* wp = (const float4*)(W +
            (((size_t)i * OUT_NODES + j) * OUT_DIM + d) * IN_DIM);
        float4 w0 = wp[0], w1 = wp[1];
        const float c = 1.0f / OUT_NODES;
        float vals[8] = {c * w0.x, c * w0.y, c * w0.z, c * w0.w,
                         c * w1.x, c * w1.y, c * w1.z, c * w1.w};
        bf16x8 vh;
#pragma unroll
        for (int e = 0; e < 8; ++e) vh[e] = (short)f2bf(vals[e]);
        *(bf16x8*)(Ahi + (size_t)s * 8) = vh;
    }
}

// ---------------------------------------------------------------------------
// k_gemm: grid 640 = (j=10, btg=4, kc=16), 256 thr (4 waves, wave -> bt).
// 1 MFMA/ktile. Fence-free split-K partials.
// ---------------------------------------------------------------------------
__global__ __launch_bounds__(256) void k_gemm(const unsigned short* __restrict__ Ahi,
                                              const unsigned short* __restrict__ Bhi,
                                              float* __restrict__ part) {
    const int bid = blockIdx.x;
    const int j = bid >> 6;            // /64
    const int r = bid & 63;
    const int btg = r >> 4;
    const int kc = r & 15;
    const int tid = threadIdx.x;
    const int lane = tid & 63;
    const int bt = btg * 4 + (tid >> 6);

    const size_t ab = (((size_t)j * KTILES + kc * KT_PER_KC) * 64 + lane) * 8;
    const size_t bb = (((size_t)bt * KTILES + kc * KT_PER_KC) * 64 + lane) * 8;

    f32x4 acc0 = {0.f, 0.f, 0.f, 0.f}, acc1 = acc0;
#pragma unroll
    for (int kt = 0; kt < KT_PER_KC; kt += 2) {
        bf16x8 a0 = *(const bf16x8*)(Ahi + ab + (size_t)kt * 512);
        bf16x8 b0 = *(const bf16x8*)(Bhi + bb + (size_t)kt * 512);
        bf16x8 a1 = *(const bf16x8*)(Ahi + ab + (size_t)(kt + 1) * 512);
        bf16x8 b1 = *(const bf16x8*)(Bhi + bb + (size_t)(kt + 1) * 512);
        acc0 = __builtin_amdgcn_mfma_f32_16x16x32_bf16(a0, b0, acc0, 0, 0, 0);
        acc1 = __builtin_amdgcn_mfma_f32_16x16x32_bf16(a1, b1, acc1, 0, 0, 0);
    }
    f32x4 acc = acc0 + acc1;
    *(f32x4*)(part + (((size_t)kc * OUT_NODES + j) * NBT + bt) * 1024 + lane * 4) = acc;
}

// ---------------------------------------------------------------------------
// k_reduce: grid 160 = (j,bt), 64 thr. Sum over kc (fixed order) + squash.
// ---------------------------------------------------------------------------
__global__ __launch_bounds__(64) void k_reduce(const float* __restrict__ part,
                                               float* __restrict__ v,
                                               float* __restrict__ out,
                                               int write_out) {
    const int j = blockIdx.x >> 4;
    const int bt = blockIdx.x & 15;
    const int lane = threadIdx.x;

    f32x4 s = {0.f, 0.f, 0.f, 0.f};
#pragma unroll
    for (int kc = 0; kc < KC; ++kc)
        s += *(const f32x4*)(part + (((size_t)kc * OUT_NODES + j) * NBT + bt) * 1024 +
                             lane * 4);
    float sq = s[0] * s[0] + s[1] * s[1] + s[2] * s[2] + s[3] * s[3];
    sq += __shfl_xor(sq, 16);
    sq += __shfl_xor(sq, 32);
    float scale = sq / ((1.0f + sq) * sqrtf(sq));
    f32x4 vv = s * scale;
    const int b = bt * 16 + (lane & 15);
    const int d0 = (lane >> 4) * 4;
    *(f32x4*)(v + ((size_t)j * BATCH + b) * OUT_DIM + d0) = vv;
    if (write_out)
        *(f32x4*)(out + ((size_t)b * OUT_NODES + j) * OUT_DIM + d0) = vv;
}

// ---------------------------------------------------------------------------
// k_agree: b-parallel (validated round 10). grid 1152 (block=i), 256 thr (b).
// W[i] in LDS; coalesced dots; wave+LDS reduce; softmax; c*W -> A-pack fold.
// ---------------------------------------------------------------------------
__global__ __launch_bounds__(256) void k_agree(const float* __restrict__ W,
                                               const float* __restrict__ xr,
                                               const float* __restrict__ v,
                                               float* __restrict__ blog,
                                               unsigned short* __restrict__ Ahi,
                                               int it) {
    __shared__ __align__(16) float W_s[1280];
    __shared__ float red[4][OUT_NODES];
    __shared__ float csh[OUT_NODES];

    const int i = blockIdx.x;
    const int tid = threadIdx.x;
    const int w = tid >> 6, lane = tid & 63;

    {
        const char* gw = (const char*)W + (size_t)i * 5120;
        ld16(gw + tid * 16, (char*)W_s + tid * 16);
        if (tid < 64) ld16(gw + 4096 + tid * 16, (char*)W_s + 4096 + tid * 16);
    }
    asm volatile("s_waitcnt vmcnt(0)" ::: "memory");
    __syncthreads();

    const int b = tid;
    const float4* xp = (const float4*)(xr + ((size_t)i * BATCH + b) * IN_DIM);
    const float4 x0 = xp[0], x1 = xp[1];

#pragma unroll 2
    for (int j = 0; j < OUT_NODES; ++j) {
        const float4* vp = (const float4*)(v + ((size_t)j * BATCH + b) * OUT_DIM);
        float4 v0 = vp[0], v1 = vp[1], v2 = vp[2], v3 = vp[3];
        float vv[16] = {v0.x, v0.y, v0.z, v0.w, v1.x, v1.y, v1.z, v1.w,
                        v2.x, v2.y, v2.z, v2.w, v3.x, v3.y, v3.z, v3.w};
        float s0 = 0.f, s1 = 0.f, s2 = 0.f, s3 = 0.f;
#pragma unroll
        for (int d = 0; d < OUT_DIM; ++d) {
            float4 w0 = *(const float4*)&W_s[(j * 16 + d) * 8];
            float4 w1 = *(const float4*)&W_s[(j * 16 + d) * 8 + 4];
            float u = w0.x * x0.x;
            u = fmaf(w0.y, x0.y, u); u = fmaf(w0.z, x0.z, u);
            u = fmaf(w0.w, x0.w, u); u = fmaf(w1.x, x1.x, u);
            u = fmaf(w1.y, x1.y, u); u = fmaf(w1.z, x1.z, u);
            u = fmaf(w1.w, x1.w, u);
            if ((d & 3) == 0) s0 = fmaf(u, vv[d], s0);
            else if ((d & 3) == 1) s1 = fmaf(u, vv[d], s1);
            else if ((d & 3) == 2) s2 = fmaf(u, vv[d], s2);
            else s3 = fmaf(u, vv[d], s3);
        }
        float sum = (s0 + s1) + (s2 + s3);
        sum += __shfl_xor(sum, 1);
        sum += __shfl_xor(sum, 2);
        sum += __shfl_xor(sum, 4);
        sum += __shfl_xor(sum, 8);
        sum += __shfl_xor(sum, 16);
        sum += __shfl_xor(sum, 32);
        if (lane == 0) red[w][j] = sum;
    }
    __syncthreads();

    if (tid < OUT_NODES) {
        float a = (red[0][tid] + red[1][tid]) + (red[2][tid] + red[3][tid]);
        float bn = (it == 0 ? 0.f : blog[i * OUT_NODES + tid]) + a * (1.0f / BATCH);
        if (it == 0) blog[i * OUT_NODES + tid] = bn;
        red[0][tid] = bn;                 // reuse red row 0 for logits
    }
    __syncthreads();

    if (tid < OUT_NODES) {
        float m = red[0][0];
#pragma unroll
        for (int jj = 1; jj < OUT_NODES; ++jj) m = fmaxf(m, red[0][jj]);
        float ssum = 0.f;
#pragma unroll
        for (int jj = 0; jj < OUT_NODES; ++jj) ssum += __expf(red[0][jj] - m);
        csh[tid] = __expf(red[0][tid] - m) / ssum;
    }
    __syncthreads();

    if (tid < OUT_NODES * OUT_DIM) {
        const int j = tid >> 4;
        const int d = tid & 15;
        const float c = csh[j];
        const float* wrow = &W_s[(j * 16 + d) * 8];
        bf16x8 vh;
#pragma unroll
        for (int e = 0; e < 8; ++e) vh[e] = (short)f2bf(c * wrow[e]);
        size_t sl = ((size_t)j * KTILES + (i >> 2)) * 64 + (i & 3) * 16 + d;
        *(bf16x8*)(Ahi + sl * 8) = vh;
    }
}

// ---------------------------------------------------------------------------
extern "C" void kernel_launch(void* const* d_in, const int* in_sizes, int n_in,
                              void* d_out, int out_size, void* d_ws, size_t ws_size,
                              hipStream_t stream) {
    const float* x = (const float*)d_in[0];  // [256,1152,8]
    const float* W = (const float*)d_in[1];  // [1152,10,16,8]
    float* out = (float*)d_out;              // [256,10,16,1]

    char* p = (char*)d_ws;
    float* xr = (float*)p;                     p += (size_t)IN_NODES * BATCH * IN_DIM * 4;
    unsigned short* Bhi = (unsigned short*)p;  p += (size_t)NBT * KTILES * 64 * 8 * 2;
    unsigned short* Ahi = (unsigned short*)p;  p += (size_t)OUT_NODES * KTILES * 64 * 8 * 2;
    float* part = (float*)p;                   p += (size_t)KC * OUT_NODES * NBT * 1024 * 4;
    float* v = (float*)p;                      p += (size_t)OUT_NODES * BATCH * OUT_DIM * 4;
    float* blog = (float*)p;                   p += (size_t)IN_NODES * OUT_NODES * 4;
    // total ~28 MB of ws

    k_prep<<<IN_NODES + 720, 256, 0, stream>>>(x, W, xr, Bhi, Ahi);

    for (int it = 0; it < 3; ++it) {
        k_gemm<<<640, 256, 0, stream>>>(Ahi, Bhi, part);
        k_reduce<<<160, 64, 0, stream>>>(part, v, out, it == 2 ? 1 : 0);
        if (it < 2)
            k_agree<<<IN_NODES, 256, 0, stream>>>(W, xr, v, blog, Ahi, it);
    }
}